// Round 2
// baseline (120.688 us; speedup 1.0000x reference)
//
#include <hip/hip_runtime.h>
#include <math.h>

typedef _Float16 half_t;
typedef _Float16 h2 __attribute__((ext_vector_type(2)));
typedef unsigned int uint;
typedef unsigned long long u64;

#define TPB 256

// pack two floats into a half2 bit pattern
__device__ __forceinline__ uint pack_h2f(float a, float b) {
  half_t ha = (half_t)a, hb = (half_t)b;
  unsigned short ua = __builtin_bit_cast(unsigned short, ha);
  unsigned short ub = __builtin_bit_cast(unsigned short, hb);
  return (uint)ua | ((uint)ub << 16);
}

// acc += silu*bw + sum_g basis[g]*w[g]   (fp16 dot2 pairs, fp32 accumulate)
// R9: w points at 5 dwords of a REGISTER array (statically indexed after full
// unroll) — weights are hoisted once per pass, replacing the per-dot8
// global/LDS reloads that dominated VMEM issue+latency in R7/R8.
__device__ __forceinline__ float dot8r(uint d0, uint d1, uint d2, uint d3,
                                       float sv, const uint* __restrict__ w,
                                       float acc) {
  acc = fmaf(sv, __uint_as_float(w[4]), acc);
#if __has_builtin(__builtin_amdgcn_fdot2)
  acc = __builtin_amdgcn_fdot2(__builtin_bit_cast(h2, d0), __builtin_bit_cast(h2, w[0]), acc, false);
  acc = __builtin_amdgcn_fdot2(__builtin_bit_cast(h2, d1), __builtin_bit_cast(h2, w[1]), acc, false);
  acc = __builtin_amdgcn_fdot2(__builtin_bit_cast(h2, d2), __builtin_bit_cast(h2, w[2]), acc, false);
  acc = __builtin_amdgcn_fdot2(__builtin_bit_cast(h2, d3), __builtin_bit_cast(h2, w[3]), acc, false);
#else
  uint dd[4] = {d0, d1, d2, d3};
#pragma unroll
  for (int k = 0; k < 4; ++k) {
    h2 f = __builtin_bit_cast(h2, dd[k]);
    h2 wv = __builtin_bit_cast(h2, w[k]);
    acc = fmaf((float)f.x, (float)wv.x, acc);
    acc = fmaf((float)f.y, (float)wv.y, acc);
  }
#endif
  return acc;
}

// Uniform-knot cubic B-spline + silu features (SoA storage, unchanged from R8).
__device__ __forceinline__ void feat_store(float x, uint* __restrict__ A,
                                           uint* __restrict__ Bq,
                                           uint* __restrict__ S) {
  float e = __expf(-x);
  float silu = x * __builtin_amdgcn_rcpf(1.0f + e);
  float s = fmaf(x, 2.5f, 5.5f);       // (x - (-2.2)) / 0.4
  float sf = floorf(s);
  float t = s - sf;
  int p = (int)sf - 3;                 // first nonzero basis index (may be <0)
  float omt = 1.0f - t, t2 = t * t;
  float B0 = (1.0f / 6.0f) * omt * omt * omt;
  float B3 = (1.0f / 6.0f) * t2 * t;
  float B1 = fmaf(0.5f * t, t2, 2.0f / 3.0f - t2);
  float B2 = 1.0f - B0 - B1 - B3;      // partition of unity
  u64 Av = ((u64)pack_h2f(B2, B3) << 32) | pack_h2f(B0, B1);
  int n = p < 0 ? -p : 0;              // halves below 0: pre-drop
  Av = (n >= 4) ? 0ull : (Av >> (16 * n));
  int pc = p < 0 ? 0 : (p > 9 ? 9 : p);
  int sh = 16 * pc;                    // 0..144
  u64 lo = (sh < 64) ? (Av << sh) : 0ull;
  u64 hi = (sh == 0) ? 0ull
         : (sh < 64) ? (Av >> (64 - sh))
         : (sh < 128) ? (Av << (sh - 64)) : 0ull;
  *(uint2*)A = make_uint2((uint)lo, (uint)(lo >> 32));
  *(uint2*)Bq = make_uint2((uint)hi, (uint)(hi >> 32));
  *S = __float_as_uint(silu);
}

// LDS layout (dwords):
//   F1A [0,1800)      900 x uint2   halves 0..3
//   F1B [1800,3600)   900 x uint2   halves 4..7
//   F1S [3600,4500)   900 x f32     silu
//   F2A [4500,5284)   392 x uint2
//   F2B [5284,6068)   392 x uint2
//   F2S [6068,6460)   392 x f32
//   Wl  [6460,6748)   packed weights, 48-dword aligned groups:
//       group o   (o=0,1):   Wl[o*48   + tap*5 + j]   layer 1
//       group wid (wid=0..3): Wl[96+wid*48 + tap*5 + j] layer 2
//       (pad dwords 45..47 of each group unused; hoisted but never read)
// Parity split: 30-col row stores col c at (c>>1)+(c&1)*15; 14-col row at
// (c>>1)+(c&1)*7 (wave-uniform parity -> lane-consecutive ds_reads).
__global__ __launch_bounds__(TPB, 5) void kan_fwd(
    const float* __restrict__ x,
    const float* __restrict__ bw1, const float* __restrict__ sw1,
    const float* __restrict__ sc1, const float* __restrict__ bw2,
    const float* __restrict__ sw2, const float* __restrict__ sc2,
    float* __restrict__ out)
{
  __shared__ __align__(16) uint lds[6748];  // 27.0 KB -> 5 blocks/CU
  uint* F1A = lds;
  uint* F1B = lds + 1800;
  uint* F1S = lds + 3600;
  uint* F2A = lds + 4500;
  uint* F2B = lds + 5284;
  uint* F2S = lds + 6068;
  uint* Wl  = lds + 6460;
  float* P = (float*)lds;    // stage>=3: 4*49*4 partials (F1 region is dead)

  const int tid = threadIdx.x;
  const float* xb = x + (size_t)blockIdx.x * 784;

  // ---- Stage 0: pack weights into LDS (replaces the separate pack_w kernel;
  // completes before the stage-1 barrier, first use is after it) ----
  if (tid < 54) {
    if (tid < 18) {
      const float scv = sc1[tid];
      uint* dst = Wl + (tid / 9) * 48 + (tid % 9) * 5;
#pragma unroll
      for (int j = 0; j < 4; ++j)
        dst[j] = pack_h2f(sw1[tid * 8 + 2 * j] * scv, sw1[tid * 8 + 2 * j + 1] * scv);
      dst[4] = __float_as_uint(bw1[tid]);
    } else {
      const int q = tid - 18;            // q = wid*9 + tap, wid = o*2+ci
      const float scv = sc2[q];
      uint* dst = Wl + 96 + (q / 9) * 48 + (q % 9) * 5;
#pragma unroll
      for (int j = 0; j < 4; ++j)
        dst[j] = pack_h2f(sw2[q * 8 + 2 * j] * scv, sw2[q * 8 + 2 * j + 1] * scv);
      dst[4] = __float_as_uint(bw2[q]);
    }
  }

  // ---- Stage 1: features of padded 30x30 input (parity-major order) ----
  for (int ii = tid; ii < 900; ii += TPB) {
    int hp = ii >= 450 ? 1 : 0;
    int k = ii - hp * 450;
    int r = k / 15, cc = k % 15;
    int c = 2 * cc + hp;
    bool inter = ((uint)(r - 1) < 28u) && ((uint)(c - 1) < 28u);
    int xi = (r - 1) * 28 + (c - 1);
    xi = min(max(xi, 0), 783);
    float xv = xb[xi];
    xv = inter ? xv : 0.0f;              // padding pixels get features of 0
    int sidx = r * 30 + cc + hp * 15;
    feat_store(xv, F1A + sidx * 2, F1B + sidx * 2, F1S + sidx);
  }
  __syncthreads();

  // ---- Stage 2: layer-1 conv (2x2 pool quad per thread) + pool + features.
  // Two o-passes, each with its 48-dword weight group hoisted to registers. ----
  if (tid < 196) {
    const int ph = tid / 14, pw = tid % 14;
#pragma unroll
    for (int o = 0; o < 2; ++o) {
      uint wv[48];
#pragma unroll
      for (int k = 0; k < 12; ++k)
        *(uint4*)&wv[k * 4] = *(const uint4*)(Wl + o * 48 + k * 4);
      float acc[4] = {0.0f, 0.0f, 0.0f, 0.0f};
#pragma unroll
      for (int r = 0; r < 4; ++r) {
#pragma unroll
        for (int c = 0; c < 4; ++c) {
          const int sidx = (2 * ph + r) * 30 + (pw + (c >> 1)) + (c & 1) * 15;
          uint2 a = *(const uint2*)(F1A + sidx * 2);
          uint2 bq = *(const uint2*)(F1B + sidx * 2);
          float sv = __uint_as_float(F1S[sidx]);
#pragma unroll
          for (int dh = 0; dh < 2; ++dh) {
            if (r - dh < 0 || r - dh > 2) continue;
#pragma unroll
            for (int dw = 0; dw < 2; ++dw) {
              if (c - dw < 0 || c - dw > 2) continue;
              const int tap = (r - dh) * 3 + (c - dw);
              acc[dh * 2 + dw] =
                  dot8r(a.x, a.y, bq.x, bq.y, sv, &wv[tap * 5], acc[dh * 2 + dw]);
            }
          }
        }
      }
      float m = fmaxf(fmaxf(acc[0], acc[1]), fmaxf(acc[2], acc[3]));
      int fidx = o * 196 + ph * 14 + (pw >> 1) + (pw & 1) * 7;
      feat_store(m, F2A + fidx * 2, F2B + fidx * 2, F2S + fidx);
    }
  }
  __syncthreads();

  // ---- Stage 3: layer-2 conv; one wave per (o,ci), lane = 7x7 pool pos.
  // The wave's 48-dword weight group is hoisted to registers once. ----
  {
    const int wid = __builtin_amdgcn_readfirstlane(tid >> 6);  // = o*2+ci
    const int lane = tid & 63;
    // features of x=0 (padding): basis halves 2..5 = {1/48, 23/48, 23/48, 1/48}
    const uint F0d1 = pack_h2f(1.0f / 48.0f, 23.0f / 48.0f);
    const uint F0d2 = pack_h2f(23.0f / 48.0f, 1.0f / 48.0f);
    if (lane < 49) {
      const int ci = wid & 1;
      const int ph = lane / 7, pw = lane % 7;
      uint wv[48];
#pragma unroll
      for (int k = 0; k < 12; ++k)
        *(uint4*)&wv[k * 4] = *(const uint4*)(Wl + 96 + wid * 48 + k * 4);
      float pa[4] = {0.0f, 0.0f, 0.0f, 0.0f};
#pragma unroll
      for (int r = 0; r < 4; ++r) {
#pragma unroll
        for (int c = 0; c < 4; ++c) {
          int row = 2 * ph + r - 1, col = 2 * pw + c - 1;
          bool ok = ((uint)row < 14u) && ((uint)col < 14u);
          int rcl = min(max(row, 0), 13), ccl = min(max(col, 0), 13);
          const int fidx = ci * 196 + rcl * 14 + (ccl >> 1) + (ccl & 1) * 7;
          uint2 a = *(const uint2*)(F2A + fidx * 2);
          uint2 bq = *(const uint2*)(F2B + fidx * 2);
          float sv = ok ? __uint_as_float(F2S[fidx]) : 0.0f;
          uint d0 = ok ? a.x : 0u;
          uint d1 = ok ? a.y : F0d1;
          uint d2 = ok ? bq.x : F0d2;
          uint d3 = ok ? bq.y : 0u;
#pragma unroll
          for (int dh = 0; dh < 2; ++dh) {
            if (r - dh < 0 || r - dh > 2) continue;
#pragma unroll
            for (int dw = 0; dw < 2; ++dw) {
              if (c - dw < 0 || c - dw > 2) continue;
              const int tap = (r - dh) * 3 + (c - dw);
              pa[dh * 2 + dw] =
                  dot8r(d0, d1, d2, d3, sv, &wv[tap * 5], pa[dh * 2 + dw]);
            }
          }
        }
      }
      *(float4*)&P[(wid * 49 + lane) * 4] = make_float4(pa[0], pa[1], pa[2], pa[3]);
    }
  }
  __syncthreads();

  // ---- Stage 4: sum input channels, 2x2 maxpool, write (2,7,7) flat ----
  if (tid < 98) {
    const int o = tid / 49, pos = tid % 49;
    const float4 p0 = *(const float4*)&P[((o * 2 + 0) * 49 + pos) * 4];
    const float4 p1 = *(const float4*)&P[((o * 2 + 1) * 49 + pos) * 4];
    float m = fmaxf(fmaxf(p0.x + p1.x, p0.y + p1.y), fmaxf(p0.z + p1.z, p0.w + p1.w));
    out[(size_t)blockIdx.x * 98 + tid] = m;
  }
}

extern "C" void kernel_launch(void* const* d_in, const int* in_sizes, int n_in,
                              void* d_out, int out_size, void* d_ws, size_t ws_size,
                              hipStream_t stream) {
  const float* x   = (const float*)d_in[0];
  const float* bw1 = (const float*)d_in[1];
  const float* sw1 = (const float*)d_in[2];
  const float* sc1 = (const float*)d_in[3];
  const float* bw2 = (const float*)d_in[4];
  const float* sw2 = (const float*)d_in[5];
  const float* sc2 = (const float*)d_in[6];
  float* out = (float*)d_out;
  const int B = in_sizes[0] / 784;  // 2048
  kan_fwd<<<B, TPB, 0, stream>>>(x, bw1, sw1, sc1, bw2, sw2, sc2, out);
}

// Round 3
// 93.583 us; speedup vs baseline: 1.2896x; 1.2896x over previous
//
#include <hip/hip_runtime.h>
#include <math.h>

typedef _Float16 half_t;
typedef _Float16 h2 __attribute__((ext_vector_type(2)));
typedef unsigned int uint;
typedef unsigned long long u64;

#define TPB 256

// pack two floats into a half2 bit pattern
__device__ __forceinline__ uint pack_h2f(float a, float b) {
  half_t ha = (half_t)a, hb = (half_t)b;
  unsigned short ua = __builtin_bit_cast(unsigned short, ha);
  unsigned short ub = __builtin_bit_cast(unsigned short, hb);
  return (uint)ua | ((uint)ub << 16);
}

// acc += silu*bw + sum_g basis[g]*w[g]   (fp16 dot2 pairs, fp32 accumulate)
// R10: weights pass BY VALUE (uint4 + uint). Entries live at uniform,
// compile-time-constant offsets of the global W array -> compiler emits CSE'd
// s_load_dwordx4 into SGPRs. No local arrays, no address-taking -> the R9
// scratch-spill failure mode (VGPR=48, 140 MB scratch traffic) is impossible.
__device__ __forceinline__ float dot8v(uint d0, uint d1, uint d2, uint d3,
                                       float sv, uint4 wa, uint wb, float acc) {
  acc = fmaf(sv, __uint_as_float(wb), acc);
#if __has_builtin(__builtin_amdgcn_fdot2)
  acc = __builtin_amdgcn_fdot2(__builtin_bit_cast(h2, d0), __builtin_bit_cast(h2, wa.x), acc, false);
  acc = __builtin_amdgcn_fdot2(__builtin_bit_cast(h2, d1), __builtin_bit_cast(h2, wa.y), acc, false);
  acc = __builtin_amdgcn_fdot2(__builtin_bit_cast(h2, d2), __builtin_bit_cast(h2, wa.z), acc, false);
  acc = __builtin_amdgcn_fdot2(__builtin_bit_cast(h2, d3), __builtin_bit_cast(h2, wa.w), acc, false);
#else
  uint dd[4] = {d0, d1, d2, d3};
  uint ww[4] = {wa.x, wa.y, wa.z, wa.w};
#pragma unroll
  for (int k = 0; k < 4; ++k) {
    h2 f = __builtin_bit_cast(h2, dd[k]);
    h2 wv = __builtin_bit_cast(h2, ww[k]);
    acc = fmaf((float)f.x, (float)wv.x, acc);
    acc = fmaf((float)f.y, (float)wv.y, acc);
  }
#endif
  return acc;
}

// Uniform-knot cubic B-spline + silu features (SoA storage).
__device__ __forceinline__ void feat_store(float x, uint* __restrict__ A,
                                           uint* __restrict__ Bq,
                                           uint* __restrict__ S) {
  float e = __expf(-x);
  float silu = x * __builtin_amdgcn_rcpf(1.0f + e);
  float s = fmaf(x, 2.5f, 5.5f);       // (x - (-2.2)) / 0.4
  float sf = floorf(s);
  float t = s - sf;
  int p = (int)sf - 3;                 // first nonzero basis index (may be <0)
  float omt = 1.0f - t, t2 = t * t;
  float B0 = (1.0f / 6.0f) * omt * omt * omt;
  float B3 = (1.0f / 6.0f) * t2 * t;
  float B1 = fmaf(0.5f * t, t2, 2.0f / 3.0f - t2);
  float B2 = 1.0f - B0 - B1 - B3;      // partition of unity
  u64 Av = ((u64)pack_h2f(B2, B3) << 32) | pack_h2f(B0, B1);
  int n = p < 0 ? -p : 0;              // halves below 0: pre-drop
  Av = (n >= 4) ? 0ull : (Av >> (16 * n));
  int pc = p < 0 ? 0 : (p > 9 ? 9 : p);
  int sh = 16 * pc;                    // 0..144
  u64 lo = (sh < 64) ? (Av << sh) : 0ull;
  u64 hi = (sh == 0) ? 0ull
         : (sh < 64) ? (Av >> (64 - sh))
         : (sh < 128) ? (Av << (sh - 64)) : 0ull;
  *(uint2*)A = make_uint2((uint)lo, (uint)(lo >> 32));
  *(uint2*)Bq = make_uint2((uint)hi, (uint)(hi >> 32));
  *S = __float_as_uint(silu);
}

// Stage-1 address/index helper: padded 30x30, parity-split columns.
__device__ __forceinline__ float s1_load(const float* __restrict__ xb, int ii,
                                         int& sidx) {
  int hp = ii >= 450 ? 1 : 0;
  int k = ii - hp * 450;
  int r = k / 15, cc = k % 15;
  int c = 2 * cc + hp;
  bool inter = ((uint)(r - 1) < 28u) && ((uint)(c - 1) < 28u);
  int xi = (r - 1) * 28 + (c - 1);
  xi = min(max(xi, 0), 783);
  float xv = xb[xi];
  sidx = r * 30 + cc + hp * 15;
  return inter ? xv : 0.0f;            // padding pixels get features of 0
}

// Packed fp16 weights in d_ws, 8-dword (32 B) aligned entries:
//   entry t       (t=0..17):  layer 1, t = o*9+tap
//   entry 18+q    (q=0..35):  layer 2, q = wid*9+tap, wid = o*2+ci
//   dwords 0..3 = 4x half2 spline weights (*scaler), dword 4 = f32 base_w
__global__ void pack_w(const float* __restrict__ bw1, const float* __restrict__ sw1,
                       const float* __restrict__ sc1, const float* __restrict__ bw2,
                       const float* __restrict__ sw2, const float* __restrict__ sc2,
                       uint* __restrict__ W) {
  const int t = threadIdx.x;
  if (t < 18) {
    const float scv = sc1[t];
    uint* dst = W + t * 8;
#pragma unroll
    for (int j = 0; j < 4; ++j)
      dst[j] = pack_h2f(sw1[t * 8 + 2 * j] * scv, sw1[t * 8 + 2 * j + 1] * scv);
    dst[4] = __float_as_uint(bw1[t]);
  } else if (t < 54) {
    const int q = t - 18;
    const float scv = sc2[q];
    uint* dst = W + t * 8;
#pragma unroll
    for (int j = 0; j < 4; ++j)
      dst[j] = pack_h2f(sw2[q * 8 + 2 * j] * scv, sw2[q * 8 + 2 * j + 1] * scv);
    dst[4] = __float_as_uint(bw2[q]);
  }
}

// LDS layout (dwords), SoA + parity-split columns:
//   F1A [0,1800)      900 x uint2   halves 0..3
//   F1B [1800,3600)   900 x uint2   halves 4..7
//   F1S [3600,4500)   900 x f32     silu
//   F2A [4500,5284)   392 x uint2
//   F2B [5284,6068)   392 x uint2
//   F2S [6068,6460)   392 x f32
// Parity split: 30-col row stores col c at (c>>1)+(c&1)*15; 14-col row at
// (c>>1)+(c&1)*7 (wave-uniform parity -> lane-consecutive ds_reads).
// 25.8 KB LDS -> 6 blocks/CU (launch_bounds 6; VGPR cap 80, demand ~60).
__global__ __launch_bounds__(TPB, 6) void kan_fwd(
    const float* __restrict__ x, const uint* __restrict__ W,
    float* __restrict__ out)
{
  __shared__ __align__(16) uint lds[6460];
  uint* F1A = lds;
  uint* F1B = lds + 1800;
  uint* F1S = lds + 3600;
  uint* F2A = lds + 4500;
  uint* F2B = lds + 5284;
  uint* F2S = lds + 6068;
  float* P = (float*)lds;    // stage>=3: 4*49*4 partials (F1 region is dead)

  const int tid = threadIdx.x;
  const float* xb = x + (size_t)blockIdx.x * 784;

  // ---- Stage 1: features of padded 30x30 input ----
  // Four independent loads issued up front (one HBM round-trip on the
  // critical path instead of four serialized ones), then the stores.
  {
    int s0, s1i, s2i, s3i;
    const bool has3 = tid < (900 - 768);
    float x0 = s1_load(xb, tid, s0);
    float x1 = s1_load(xb, tid + 256, s1i);
    float x2 = s1_load(xb, tid + 512, s2i);
    float x3 = s1_load(xb, has3 ? tid + 768 : tid, s3i);
    feat_store(x0, F1A + s0 * 2, F1B + s0 * 2, F1S + s0);
    feat_store(x1, F1A + s1i * 2, F1B + s1i * 2, F1S + s1i);
    feat_store(x2, F1A + s2i * 2, F1B + s2i * 2, F1S + s2i);
    if (has3) feat_store(x3, F1A + s3i * 2, F1B + s3i * 2, F1S + s3i);
  }
  __syncthreads();

  // ---- Stage 2: layer-1 conv (2x2 pool quad per thread) + pool + features ----
  if (tid < 196) {
    const int ph = tid / 14, pw = tid % 14;
    float acc[2][4];
#pragma unroll
    for (int o = 0; o < 2; ++o)
#pragma unroll
      for (int q = 0; q < 4; ++q) acc[o][q] = 0.0f;
#pragma unroll
    for (int r = 0; r < 4; ++r) {
#pragma unroll
      for (int c = 0; c < 4; ++c) {
        const int sidx = (2 * ph + r) * 30 + (pw + (c >> 1)) + (c & 1) * 15;
        uint2 a = *(const uint2*)(F1A + sidx * 2);
        uint2 bq = *(const uint2*)(F1B + sidx * 2);
        float sv = __uint_as_float(F1S[sidx]);
#pragma unroll
        for (int dh = 0; dh < 2; ++dh) {
          if (r - dh < 0 || r - dh > 2) continue;
#pragma unroll
          for (int dw = 0; dw < 2; ++dw) {
            if (c - dw < 0 || c - dw > 2) continue;
            const int tap = (r - dh) * 3 + (c - dw);
#pragma unroll
            for (int o = 0; o < 2; ++o) {
              const uint4 wa = *(const uint4*)(W + (o * 9 + tap) * 8);
              const uint wb = W[(o * 9 + tap) * 8 + 4];
              acc[o][dh * 2 + dw] =
                  dot8v(a.x, a.y, bq.x, bq.y, sv, wa, wb, acc[o][dh * 2 + dw]);
            }
          }
        }
      }
    }
#pragma unroll
    for (int o = 0; o < 2; ++o) {
      float m = fmaxf(fmaxf(acc[o][0], acc[o][1]), fmaxf(acc[o][2], acc[o][3]));
      int fidx = o * 196 + ph * 14 + (pw >> 1) + (pw & 1) * 7;
      feat_store(m, F2A + fidx * 2, F2B + fidx * 2, F2S + fidx);
    }
  }
  __syncthreads();

  // ---- Stage 3: layer-2 conv; one wave per (o,ci), lane = 7x7 pool pos ----
  {
    const int wid = __builtin_amdgcn_readfirstlane(tid >> 6);  // = o*2+ci
    const int lane = tid & 63;
    // features of x=0 (padding): basis halves 2..5 = {1/48, 23/48, 23/48, 1/48}
    const uint F0d1 = pack_h2f(1.0f / 48.0f, 23.0f / 48.0f);
    const uint F0d2 = pack_h2f(23.0f / 48.0f, 1.0f / 48.0f);
    if (lane < 49) {
      const int ci = wid & 1;
      const int ph = lane / 7, pw = lane % 7;
      float pa[4] = {0.0f, 0.0f, 0.0f, 0.0f};
#pragma unroll
      for (int r = 0; r < 4; ++r) {
#pragma unroll
        for (int c = 0; c < 4; ++c) {
          int row = 2 * ph + r - 1, col = 2 * pw + c - 1;
          bool ok = ((uint)row < 14u) && ((uint)col < 14u);
          int rcl = min(max(row, 0), 13), ccl = min(max(col, 0), 13);
          const int fidx = ci * 196 + rcl * 14 + (ccl >> 1) + (ccl & 1) * 7;
          uint2 a = *(const uint2*)(F2A + fidx * 2);
          uint2 bq = *(const uint2*)(F2B + fidx * 2);
          float sv = ok ? __uint_as_float(F2S[fidx]) : 0.0f;
          uint d0 = ok ? a.x : 0u;
          uint d1 = ok ? a.y : F0d1;
          uint d2 = ok ? bq.x : F0d2;
          uint d3 = ok ? bq.y : 0u;
#pragma unroll
          for (int dh = 0; dh < 2; ++dh) {
            if (r - dh < 0 || r - dh > 2) continue;
#pragma unroll
            for (int dw = 0; dw < 2; ++dw) {
              if (c - dw < 0 || c - dw > 2) continue;
              const int tap = (r - dh) * 3 + (c - dw);
              const uint4 wa = *(const uint4*)(W + (18 + wid * 9 + tap) * 8);
              const uint wb = W[(18 + wid * 9 + tap) * 8 + 4];
              pa[dh * 2 + dw] =
                  dot8v(d0, d1, d2, d3, sv, wa, wb, pa[dh * 2 + dw]);
            }
          }
        }
      }
      *(float4*)&P[(wid * 49 + lane) * 4] = make_float4(pa[0], pa[1], pa[2], pa[3]);
    }
  }
  __syncthreads();

  // ---- Stage 4: sum input channels, 2x2 maxpool, write (2,7,7) flat ----
  if (tid < 98) {
    const int o = tid / 49, pos = tid % 49;
    const float4 p0 = *(const float4*)&P[((o * 2 + 0) * 49 + pos) * 4];
    const float4 p1 = *(const float4*)&P[((o * 2 + 1) * 49 + pos) * 4];
    float m = fmaxf(fmaxf(p0.x + p1.x, p0.y + p1.y), fmaxf(p0.z + p1.z, p0.w + p1.w));
    out[(size_t)blockIdx.x * 98 + tid] = m;
  }
}

extern "C" void kernel_launch(void* const* d_in, const int* in_sizes, int n_in,
                              void* d_out, int out_size, void* d_ws, size_t ws_size,
                              hipStream_t stream) {
  const float* x   = (const float*)d_in[0];
  const float* bw1 = (const float*)d_in[1];
  const float* sw1 = (const float*)d_in[2];
  const float* sc1 = (const float*)d_in[3];
  const float* bw2 = (const float*)d_in[4];
  const float* sw2 = (const float*)d_in[5];
  const float* sc2 = (const float*)d_in[6];
  float* out = (float*)d_out;
  uint* W = (uint*)d_ws;  // 432 dwords (54 entries x 8)
  const int B = in_sizes[0] / 784;  // 2048
  pack_w<<<1, 64, 0, stream>>>(bw1, sw1, sc1, bw2, sw2, sc2, W);
  kan_fwd<<<B, TPB, 0, stream>>>(x, W, out);
}